// Round 4
// baseline (1057.308 us; speedup 1.0000x reference)
//
#include <hip/hip_runtime.h>
#include <hip/hip_fp16.h>
#include <math.h>

#define N_NODES 40000
#define N_EDGES 640000
#define N_GRAPHS 32
#define HDIM 128
#define NHEADS 4
#define CDIM 32
#define NLAYERS 4
#define ODIM 100
#define SCAN_B 256
#define SCAN_NBLK ((N_NODES + SCAN_B - 1) / SCAN_B)   // 157
#define M_PAD 40064                                   // 313 * 128
#define POOL_CHUNK 256
#define POOL_NBLK ((N_NODES + POOL_CHUNK - 1) / POOL_CHUNK)  // 157

typedef __bf16 bf16_t;
typedef bf16_t bf16x8 __attribute__((ext_vector_type(8)));
typedef float f32x4 __attribute__((ext_vector_type(4)));

// ---------------------------------------------------------------------------
// h = x @ node_w + node_b   ([N,4]@[4,128]) -> bf16 feature buffer
__global__ void nodeproj_kernel(const float* __restrict__ x,
                                const float* __restrict__ w,
                                const float* __restrict__ b,
                                bf16_t* __restrict__ hb) {
    int idx = blockIdx.x * blockDim.x + threadIdx.x;
    if (idx >= N_NODES * HDIM) return;
    int n = idx >> 7, c = idx & 127;
    float s = b[c];
    s += x[n * 4 + 0] * w[0 * HDIM + c];
    s += x[n * 4 + 1] * w[1 * HDIM + c];
    s += x[n * 4 + 2] * w[2 * HDIM + c];
    s += x[n * 4 + 3] * w[3 * HDIM + c];
    hb[idx] = (bf16_t)s;
}

// ---------------------------------------------------------------------------
// Fold edge_proj into per-layer matrices:
//   Me[i] = edge_w @ We[i]  ([5,128]),  ce[i] = edge_b @ We[i]  ([128])
__global__ void fold_edge_kernel(const float* __restrict__ edge_w,
                                 const float* __restrict__ edge_b,
                                 const float* __restrict__ We,
                                 float* __restrict__ Me_all,
                                 float* __restrict__ ce_all) {
    int blk = blockIdx.x;
    int i = blk / 6, j = blk % 6;
    int c = threadIdx.x;
    const float* W = We + (size_t)i * HDIM * HDIM;
    float s = 0.0f;
    if (j < 5) {
        for (int k = 0; k < HDIM; ++k) s += edge_w[j * HDIM + k] * W[k * HDIM + c];
        Me_all[i * 5 * HDIM + j * HDIM + c] = s;
    } else {
        for (int k = 0; k < HDIM; ++k) s += edge_b[k] * W[k * HDIM + c];
        ce_all[i * HDIM + c] = s;
    }
}

// ---------------------------------------------------------------------------
// Convert all layer weights to bf16, transposed to [n][k] for MFMA B-frags.
__global__ void convert_w_kernel(const float* __restrict__ Wq, const float* __restrict__ Wk,
                                 const float* __restrict__ Wv, const float* __restrict__ Ws,
                                 bf16_t* __restrict__ Wtb) {
    int b = blockIdx.x;
    int n = b & 127;
    int matli = b >> 7;
    int mat = matli & 3, li = matli >> 2;
    int kk = threadIdx.x;
    const float* W = (mat == 0 ? Wq : mat == 1 ? Wk : mat == 2 ? Wv : Ws) + (size_t)li * HDIM * HDIM;
    Wtb[((size_t)(li * 4 + mat) * HDIM + n) * HDIM + kk] = (bf16_t)W[kk * HDIM + n];
}

// ---------------------------------------------------------------------------
// CSR build
__global__ void count_deg_kernel(const int* __restrict__ ei, int* __restrict__ deg) {
    int e = blockIdx.x * blockDim.x + threadIdx.x;
    if (e >= N_EDGES) return;
    atomicAdd(&deg[ei[N_EDGES + e]], 1);
}

__global__ void scan1_kernel(const int* __restrict__ deg,
                             int* __restrict__ rowptr, int* __restrict__ bsum) {
    __shared__ int sd[SCAN_B];
    int tid = threadIdx.x;
    int i = blockIdx.x * SCAN_B + tid;
    int v = (i < N_NODES) ? deg[i] : 0;
    sd[tid] = v;
    __syncthreads();
#pragma unroll
    for (int off = 1; off < SCAN_B; off <<= 1) {
        int tmp = (tid >= off) ? sd[tid - off] : 0;
        __syncthreads();
        sd[tid] += tmp;
        __syncthreads();
    }
    if (i < N_NODES) rowptr[i] = sd[tid] - v;
    if (tid == SCAN_B - 1) bsum[blockIdx.x] = sd[tid];
}

__global__ void scan2_kernel(const int* __restrict__ bsum, int* __restrict__ bscan) {
    __shared__ int sd[SCAN_B];
    int tid = threadIdx.x;
    int v = (tid < SCAN_NBLK) ? bsum[tid] : 0;
    sd[tid] = v;
    __syncthreads();
#pragma unroll
    for (int off = 1; off < SCAN_B; off <<= 1) {
        int tmp = (tid >= off) ? sd[tid - off] : 0;
        __syncthreads();
        sd[tid] += tmp;
        __syncthreads();
    }
    if (tid < SCAN_NBLK) bscan[tid] = sd[tid] - v;
}

__global__ void scan3_kernel(int* __restrict__ rowptr, const int* __restrict__ bscan) {
    int i = blockIdx.x * SCAN_B + threadIdx.x;
    if (i < N_NODES) rowptr[i] += bscan[blockIdx.x];
    if (i == 0) rowptr[N_NODES] = N_EDGES;
}

// scatter src + reordered edge_attr into CSR position order
__global__ void fill_csr_kernel(const int* __restrict__ ei,
                                const float* __restrict__ ea,
                                const int* __restrict__ rowptr,
                                int* __restrict__ cursor,
                                int* __restrict__ srcarr,
                                float* __restrict__ ea5) {
    int e = blockIdx.x * blockDim.x + threadIdx.x;
    if (e >= N_EDGES) return;
    int src = ei[e], dst = ei[N_EDGES + e];
    int pos = atomicAdd(&cursor[dst], 1);
    int p = rowptr[dst] + pos;
    srcarr[p] = src;
#pragma unroll
    for (int j = 0; j < 5; ++j) ea5[(size_t)p * 5 + j] = ea[(size_t)e * 5 + j];
}

// ---------------------------------------------------------------------------
// Fused 4-projection bf16 MFMA GEMM.
// mat0 -> q fp32; mat1/mat2 -> packed fp16 kv (k=low half, v=high half);
// mat3 -> skip fp32.
__global__ __launch_bounds__(256) void gemm_mfma(
    const bf16_t* __restrict__ hb, const bf16_t* __restrict__ Wt,
    const float* __restrict__ bq, const float* __restrict__ bk,
    const float* __restrict__ bv, const float* __restrict__ bs,
    float* __restrict__ qo, __half* __restrict__ kvh,
    float* __restrict__ so) {
    __shared__ bf16_t Ash[128 * 128];
    __shared__ bf16_t Bsh[128 * 128];
    int tid = threadIdx.x;
    int mat = blockIdx.y;
    const bf16_t* W = Wt + (size_t)mat * HDIM * HDIM;
    const float* bias = (mat == 0) ? bq : (mat == 1) ? bk : (mat == 2) ? bv : bs;
    float* out = (mat == 0) ? qo : so;
    int row0 = blockIdx.x * 128;

    {   // stage A and B tiles (XOR-swizzled 16B granules: 2-way aliasing = free)
        int r = tid >> 4, g = tid & 15;
#pragma unroll
        for (int p = 0; p < 8; ++p) {
            int rr = p * 16 + r;
            int sw = (g ^ (rr & 15)) << 3;
            bf16x8 a = *(const bf16x8*)(hb + (size_t)(row0 + rr) * HDIM + g * 8);
            *(bf16x8*)(Ash + rr * 128 + sw) = a;
            bf16x8 bvec = *(const bf16x8*)(W + (size_t)rr * HDIM + g * 8);
            *(bf16x8*)(Bsh + rr * 128 + sw) = bvec;
        }
    }
    __syncthreads();

    int lane = tid & 63, wave = tid >> 6;
    int wr = (wave >> 1) * 64, wc = (wave & 1) * 64;
    int lm = lane & 15, quad = lane >> 4;

    f32x4 acc[4][4];
#pragma unroll
    for (int i = 0; i < 4; ++i)
#pragma unroll
        for (int j = 0; j < 4; ++j) acc[i][j] = (f32x4){0.f, 0.f, 0.f, 0.f};

#pragma unroll
    for (int ks = 0; ks < 4; ++ks) {
        int g = ks * 4 + quad;
        int sw = (g ^ lm) << 3;
        bf16x8 af[4], bf[4];
#pragma unroll
        for (int t = 0; t < 4; ++t) {
            int ar = wr + t * 16 + lm;
            af[t] = *(const bf16x8*)(Ash + ar * 128 + sw);
            int br = wc + t * 16 + lm;
            bf[t] = *(const bf16x8*)(Bsh + br * 128 + sw);
        }
#pragma unroll
        for (int i = 0; i < 4; ++i)
#pragma unroll
            for (int j = 0; j < 4; ++j)
                acc[i][j] = __builtin_amdgcn_mfma_f32_16x16x32_bf16(af[i], bf[j], acc[i][j], 0, 0, 0);
    }

#pragma unroll
    for (int i = 0; i < 4; ++i) {
        int rbase = row0 + wr + i * 16 + quad * 4;
#pragma unroll
        for (int j = 0; j < 4; ++j) {
            int col = wc + j * 16 + lm;
            float bcol = bias[col];
#pragma unroll
            for (int r = 0; r < 4; ++r) {
                int row = rbase + r;
                if (row < N_NODES) {
                    float val = acc[i][j][r] + bcol;
                    if (mat == 0 || mat == 3) {
                        out[(size_t)row * HDIM + col] = val;
                    } else {
                        kvh[((size_t)row * HDIM + col) * 2 + (mat - 1)] = __float2half(val);
                    }
                }
            }
        }
    }
}

// ---------------------------------------------------------------------------
// Fused per-dst-node attention + skip + LayerNorm + ReLU, algebraically
// restructured: edge-embedding handled via per-node precomputed dots
// (score side) and per-head weighted-attr accumulators (value side).
// One block (128 threads = 2 waves) per node; thread t owns channel t.
__global__ __launch_bounds__(128) void agg_kernel(
    const int* __restrict__ srcarr, const int* __restrict__ rowptr,
    const float* __restrict__ ea5,
    const float* __restrict__ q, const __half2* __restrict__ kv,
    const float* __restrict__ Me, const float* __restrict__ ce,
    const float* __restrict__ skip,
    const float* __restrict__ lg, const float* __restrict__ lb,
    bf16_t* __restrict__ hbout) {
    __shared__ float wred[2];
    int n = blockIdx.x;
    int t = threadIdx.x;
    int c = t & 31;
    int lane = t & 63;

    float qv = q[(size_t)n * HDIM + t] * 0.17677669529663687f;  // scale folded
    float cw = ce[t];
    float mw[5];
#pragma unroll
    for (int j = 0; j < 5; ++j) mw[j] = Me[j * HDIM + t];

    // per-node precompute: myq = scale * (c<5 ? q.Me_c : c==5 ? q.ce : 0)
    float myq = 0.0f;
#pragma unroll
    for (int j = 0; j < 6; ++j) {
        float p = qv * ((j < 5) ? mw[j] : cw);
        p += __shfl_xor(p, 16, 32);
        p += __shfl_xor(p, 8, 32);
        p += __shfl_xor(p, 4, 32);
        p += __shfl_xor(p, 2, 32);
        p += __shfl_xor(p, 1, 32);
        if (c == j) myq = p;
    }

    int beg = rowptr[n], end = rowptr[n + 1];
    float m = -INFINITY, l = 0.0f, o = 0.0f, ab = 0.0f;
    for (int idx = beg; idx < end; ++idx) {
        int src = srcarr[idx];
        float aval = (c < 5) ? ea5[(size_t)idx * 5 + c] : 1.0f;
        __half2 kvv = kv[(size_t)src * HDIM + t];
        float kf = __low2float(kvv);
        float vf = __high2float(kvv);
        float p = fmaf(qv, kf, myq * aval);   // q.k part + ev-score part
        p += __shfl_xor(p, 16, 32);
        p += __shfl_xor(p, 8, 32);
        p += __shfl_xor(p, 4, 32);
        p += __shfl_xor(p, 2, 32);
        p += __shfl_xor(p, 1, 32);
        float m_new = fmaxf(m, p);
        float sc = __expf(m - m_new);   // 0 on first edge
        float pe = __expf(p - m_new);
        o = o * sc + pe * vf;
        l = l * sc + pe;
        ab = ab * sc + pe * aval;       // lanes c<5: sum pe*a_c (value-side ev)
        m = m_new;
    }

    // msg = (o + l*ce + sum_j Me_j * ab_j) / (l + 1e-16); isolated node -> 0
    float num = fmaf(l, cw, o);
#pragma unroll
    for (int j = 0; j < 5; ++j) {
        float abj = __shfl(ab, (lane & 32) + j, 64);
        num = fmaf(mw[j], abj, num);
    }
    float msg = num / (l + 1e-16f);
    float val = skip[(size_t)n * HDIM + t] + msg;

    // LayerNorm over 128 channels
    float s = val;
#pragma unroll
    for (int mask = 32; mask >= 1; mask >>= 1) s += __shfl_xor(s, mask, 64);
    if ((t & 63) == 0) wred[t >> 6] = s;
    __syncthreads();
    float mu = (wred[0] + wred[1]) * (1.0f / HDIM);
    float d = val - mu;
    float s2 = d * d;
#pragma unroll
    for (int mask = 32; mask >= 1; mask >>= 1) s2 += __shfl_xor(s2, mask, 64);
    __syncthreads();
    if ((t & 63) == 0) wred[t >> 6] = s2;
    __syncthreads();
    float var = (wred[0] + wred[1]) * (1.0f / HDIM);
    float y = d * rsqrtf(var + 1e-5f) * lg[t] + lb[t];
    y = fmaxf(y, 0.0f);
    hbout[(size_t)n * HDIM + t] = (bf16_t)y;
}

// ---------------------------------------------------------------------------
// Chunked mean-pool over sorted batch (bf16 input, fp32 accumulate)
__global__ __launch_bounds__(128) void pool_kernel(const bf16_t* __restrict__ h,
                                                   const int* __restrict__ batch,
                                                   float* __restrict__ pool,
                                                   float* __restrict__ cnt) {
    int t = threadIdx.x;
    int n0 = blockIdx.x * POOL_CHUNK;
    int n1 = n0 + POOL_CHUNK;
    if (n1 > N_NODES) n1 = N_NODES;
    int gcur = batch[n0];
    int cstart = n0;
    float acc = 0.0f;
    for (int n = n0; n < n1; ++n) {
        int g = batch[n];
        if (g != gcur) {
            atomicAdd(&pool[gcur * HDIM + t], acc);
            if (t == 0) atomicAdd(&cnt[gcur], (float)(n - cstart));
            acc = 0.0f;
            gcur = g;
            cstart = n;
        }
        acc += (float)h[(size_t)n * HDIM + t];
    }
    atomicAdd(&pool[gcur * HDIM + t], acc);
    if (t == 0) atomicAdd(&cnt[gcur], (float)(n1 - cstart));
}

// ---------------------------------------------------------------------------
__global__ void heads_kernel(const float* __restrict__ pool,
                             const float* __restrict__ cnt,
                             const float* __restrict__ dw1, const float* __restrict__ db1,
                             const float* __restrict__ dw2, const float* __restrict__ db2,
                             const float* __restrict__ tw1, const float* __restrict__ tb1,
                             const float* __restrict__ tw2, const float* __restrict__ tb2,
                             float* __restrict__ outp) {
    int g = blockIdx.x, t = threadIdx.x;
    __shared__ float hg[HDIM];
    __shared__ float hid[64];
    float c = fmaxf(cnt[g], 1.0f);
    hg[t] = pool[g * HDIM + t] / c;
    __syncthreads();
    if (t < 64) {
        float s = db1[t];
        for (int i = 0; i < HDIM; ++i) s += hg[i] * dw1[i * 64 + t];
        hid[t] = fmaxf(s, 0.0f);
    }
    __syncthreads();
    if (t < ODIM) {
        float s = db2[t];
        for (int j = 0; j < 64; ++j) s += hid[j] * dw2[j * ODIM + t];
        outp[g * ODIM + t] = s;
    }
    __syncthreads();
    if (t < 64) {
        float s = tb1[t];
        for (int i = 0; i < HDIM; ++i) s += hg[i] * tw1[i * 64 + t];
        hid[t] = fmaxf(s, 0.0f);
    }
    __syncthreads();
    if (t < ODIM) {
        float s = tb2[t];
        for (int j = 0; j < 64; ++j) s += hid[j] * tw2[j * ODIM + t];
        outp[N_GRAPHS * ODIM + g * ODIM + t] = s;
    }
}

// ---------------------------------------------------------------------------
extern "C" void kernel_launch(void* const* d_in, const int* in_sizes, int n_in,
                              void* d_out, int out_size, void* d_ws, size_t ws_size,
                              hipStream_t stream) {
    const float* x        = (const float*)d_in[0];
    const float* ea       = (const float*)d_in[1];
    const float* node_w   = (const float*)d_in[2];
    const float* node_b   = (const float*)d_in[3];
    const float* edge_w   = (const float*)d_in[4];
    const float* edge_b   = (const float*)d_in[5];
    const float* Wq       = (const float*)d_in[6];
    const float* bq       = (const float*)d_in[7];
    const float* Wk       = (const float*)d_in[8];
    const float* bk       = (const float*)d_in[9];
    const float* Wv       = (const float*)d_in[10];
    const float* bv       = (const float*)d_in[11];
    const float* We       = (const float*)d_in[12];
    const float* Wskip    = (const float*)d_in[13];
    const float* bskip    = (const float*)d_in[14];
    const float* ln_g     = (const float*)d_in[15];
    const float* ln_b     = (const float*)d_in[16];
    const float* dw1      = (const float*)d_in[17];
    const float* db1      = (const float*)d_in[18];
    const float* dw2      = (const float*)d_in[19];
    const float* db2      = (const float*)d_in[20];
    const float* tw1      = (const float*)d_in[21];
    const float* tb1      = (const float*)d_in[22];
    const float* tw2      = (const float*)d_in[23];
    const float* tb2      = (const float*)d_in[24];
    const int*   ei       = (const int*)d_in[25];
    const int*   batch    = (const int*)d_in[26];
    float* out = (float*)d_out;
    (void)in_sizes; (void)n_in; (void)out_size; (void)ws_size;

    // ---- workspace carve (256B aligned) ----
    char* wsb = (char*)d_ws;
    size_t off = 0;
    auto carve = [&](size_t bytes) -> void* {
        void* p = wsb + off;
        off += (bytes + 255) & ~(size_t)255;
        return p;
    };
    bf16_t* hbuf   = (bf16_t*)carve((size_t)M_PAD * HDIM * 2);
    float*  q      = (float*) carve((size_t)N_NODES * HDIM * 4);
    __half* kvh    = (__half*)carve((size_t)N_NODES * HDIM * 2 * 2);  // interleaved k,v
    float*  ob     = (float*) carve((size_t)N_NODES * HDIM * 4);      // skip buffer
    bf16_t* Wtb    = (bf16_t*)carve((size_t)NLAYERS * 4 * HDIM * HDIM * 2);
    int*    srcarr = (int*)   carve((size_t)N_EDGES * 4);
    float*  ea5    = (float*) carve((size_t)N_EDGES * 5 * 4);
    int*    deg    = (int*)   carve((size_t)N_NODES * 4);
    int*    rowptr = (int*)   carve((size_t)(N_NODES + 1) * 4);
    int*    cursor = (int*)   carve((size_t)N_NODES * 4);
    int*    bsum   = (int*)   carve((size_t)SCAN_NBLK * 4);
    int*    bscan  = (int*)   carve((size_t)SCAN_NBLK * 4);
    float*  Me_all = (float*) carve((size_t)NLAYERS * 5 * HDIM * 4);
    float*  ce_all = (float*) carve((size_t)NLAYERS * HDIM * 4);
    float*  pool   = (float*) carve((size_t)N_GRAPHS * HDIM * 4);
    float*  cnt    = (float*) carve((size_t)N_GRAPHS * 4);

    const int nthreads = 256;
    const int e_blocks  = (N_EDGES + nthreads - 1) / nthreads;
    const int nc_blocks = (N_NODES * HDIM) / nthreads;

    // ---- CSR build ----
    hipMemsetAsync(deg, 0, (size_t)N_NODES * 4, stream);
    hipMemsetAsync(cursor, 0, (size_t)N_NODES * 4, stream);
    count_deg_kernel<<<e_blocks, nthreads, 0, stream>>>(ei, deg);
    scan1_kernel<<<SCAN_NBLK, SCAN_B, 0, stream>>>(deg, rowptr, bsum);
    scan2_kernel<<<1, SCAN_B, 0, stream>>>(bsum, bscan);
    scan3_kernel<<<SCAN_NBLK, SCAN_B, 0, stream>>>(rowptr, bscan);
    fill_csr_kernel<<<e_blocks, nthreads, 0, stream>>>(ei, ea, rowptr, cursor, srcarr, ea5);

    // ---- projections / weight prep ----
    hipMemsetAsync(hbuf + (size_t)N_NODES * HDIM, 0,
                   (size_t)(M_PAD - N_NODES) * HDIM * 2, stream);  // zero pad rows
    nodeproj_kernel<<<nc_blocks, nthreads, 0, stream>>>(x, node_w, node_b, hbuf);
    fold_edge_kernel<<<NLAYERS * 6, HDIM, 0, stream>>>(edge_w, edge_b, We, Me_all, ce_all);
    convert_w_kernel<<<NLAYERS * 4 * HDIM, HDIM, 0, stream>>>(Wq, Wk, Wv, Wskip, Wtb);

    for (int i = 0; i < NLAYERS; ++i) {
        const float* Me = Me_all + i * 5 * HDIM;
        const float* ce = ce_all + i * HDIM;
        gemm_mfma<<<dim3(M_PAD / 128, 4), 256, 0, stream>>>(
            hbuf, Wtb + (size_t)i * 4 * HDIM * HDIM,
            bq + i * HDIM, bk + i * HDIM, bv + i * HDIM, bskip + i * HDIM,
            q, kvh, ob);
        agg_kernel<<<N_NODES, 128, 0, stream>>>(srcarr, rowptr, ea5, q, (const __half2*)kvh,
                                                Me, ce, ob,
                                                ln_g + i * HDIM, ln_b + i * HDIM, hbuf);
    }

    hipMemsetAsync(pool, 0, (size_t)N_GRAPHS * HDIM * 4, stream);
    hipMemsetAsync(cnt, 0, (size_t)N_GRAPHS * 4, stream);
    pool_kernel<<<POOL_NBLK, HDIM, 0, stream>>>(hbuf, batch, pool, cnt);
    heads_kernel<<<N_GRAPHS, HDIM, 0, stream>>>(pool, cnt, dw1, db1, dw2, db2,
                                                tw1, tb1, tw2, tb2, out);
}

// Round 6
// 843.357 us; speedup vs baseline: 1.2537x; 1.2537x over previous
//
#include <hip/hip_runtime.h>
#include <hip/hip_fp16.h>
#include <math.h>

#define N_NODES 40000
#define N_EDGES 640000
#define N_GRAPHS 32
#define HDIM 128
#define NHEADS 4
#define CDIM 32
#define NLAYERS 4
#define ODIM 100
#define SCAN_B 256
#define SCAN_NBLK ((N_NODES + SCAN_B - 1) / SCAN_B)   // 157
#define M_PAD 40064                                   // 313 * 128
#define POOL_CHUNK 256
#define POOL_NBLK ((N_NODES + POOL_CHUNK - 1) / POOL_CHUNK)  // 157
#define SCALE 0.17677669529663687f                    // 1/sqrt(32)

typedef __bf16 bf16_t;
typedef bf16_t bf16x8 __attribute__((ext_vector_type(8)));
typedef float f32x4 __attribute__((ext_vector_type(4)));

// ---------------------------------------------------------------------------
// h = x @ node_w + node_b   ([N,4]@[4,128]) -> bf16 feature buffer
__global__ void nodeproj_kernel(const float* __restrict__ x,
                                const float* __restrict__ w,
                                const float* __restrict__ b,
                                bf16_t* __restrict__ hb) {
    int idx = blockIdx.x * blockDim.x + threadIdx.x;
    if (idx >= N_NODES * HDIM) return;
    int n = idx >> 7, c = idx & 127;
    float s = b[c];
    s += x[n * 4 + 0] * w[0 * HDIM + c];
    s += x[n * 4 + 1] * w[1 * HDIM + c];
    s += x[n * 4 + 2] * w[2 * HDIM + c];
    s += x[n * 4 + 3] * w[3 * HDIM + c];
    hb[idx] = (bf16_t)s;
}

// ---------------------------------------------------------------------------
// Me[i] = edge_w @ We[i]  ([5,128]),  ce[i] = edge_b @ We[i]  ([128])
__global__ void fold_edge_kernel(const float* __restrict__ edge_w,
                                 const float* __restrict__ edge_b,
                                 const float* __restrict__ We,
                                 float* __restrict__ Me_all,
                                 float* __restrict__ ce_all) {
    int blk = blockIdx.x;
    int i = blk / 6, j = blk % 6;
    int c = threadIdx.x;
    const float* W = We + (size_t)i * HDIM * HDIM;
    float s = 0.0f;
    if (j < 5) {
        for (int k = 0; k < HDIM; ++k) s += edge_w[j * HDIM + k] * W[k * HDIM + c];
        Me_all[i * 5 * HDIM + j * HDIM + c] = s;
    } else {
        for (int k = 0; k < HDIM; ++k) s += edge_b[k] * W[k * HDIM + c];
        ce_all[i * HDIM + c] = s;
    }
}

// ---------------------------------------------------------------------------
// CSR build
__global__ void count_deg_kernel(const int* __restrict__ ei, int* __restrict__ deg) {
    int e = blockIdx.x * blockDim.x + threadIdx.x;
    if (e >= N_EDGES) return;
    atomicAdd(&deg[ei[N_EDGES + e]], 1);
}

__global__ void scan1_kernel(const int* __restrict__ deg,
                             int* __restrict__ rowptr, int* __restrict__ bsum) {
    __shared__ int sd[SCAN_B];
    int tid = threadIdx.x;
    int i = blockIdx.x * SCAN_B + tid;
    int v = (i < N_NODES) ? deg[i] : 0;
    sd[tid] = v;
    __syncthreads();
#pragma unroll
    for (int off = 1; off < SCAN_B; off <<= 1) {
        int tmp = (tid >= off) ? sd[tid - off] : 0;
        __syncthreads();
        sd[tid] += tmp;
        __syncthreads();
    }
    if (i < N_NODES) rowptr[i] = sd[tid] - v;
    if (tid == SCAN_B - 1) bsum[blockIdx.x] = sd[tid];
}

__global__ void scan2_kernel(const int* __restrict__ bsum, int* __restrict__ bscan) {
    __shared__ int sd[SCAN_B];
    int tid = threadIdx.x;
    int v = (tid < SCAN_NBLK) ? bsum[tid] : 0;
    sd[tid] = v;
    __syncthreads();
#pragma unroll
    for (int off = 1; off < SCAN_B; off <<= 1) {
        int tmp = (tid >= off) ? sd[tid - off] : 0;
        __syncthreads();
        sd[tid] += tmp;
        __syncthreads();
    }
    if (tid < SCAN_NBLK) bscan[tid] = sd[tid] - v;
}

__global__ void scan3_kernel(int* __restrict__ rowptr, const int* __restrict__ bscan) {
    int i = blockIdx.x * SCAN_B + threadIdx.x;
    if (i < N_NODES) rowptr[i] += bscan[blockIdx.x];
    if (i == 0) rowptr[N_NODES] = N_EDGES;
}

__global__ void fill_csr_kernel(const int* __restrict__ ei,
                                const float* __restrict__ ea,
                                const int* __restrict__ rowptr,
                                int* __restrict__ cursor,
                                int* __restrict__ srcarr,
                                float* __restrict__ ea5) {
    int e = blockIdx.x * blockDim.x + threadIdx.x;
    if (e >= N_EDGES) return;
    int src = ei[e], dst = ei[N_EDGES + e];
    int pos = atomicAdd(&cursor[dst], 1);
    int p = rowptr[dst] + pos;
    srcarr[p] = src;
#pragma unroll
    for (int j = 0; j < 5; ++j) ea5[(size_t)p * 5 + j] = ea[(size_t)e * 5 + j];
}

// ---------------------------------------------------------------------------
// Convert weights to bf16 [n][k]; Wk pre-scaled by 1/sqrt(C).
__global__ void convert_w_kernel(const float* __restrict__ Wq, const float* __restrict__ Wk,
                                 const float* __restrict__ Wv, const float* __restrict__ Ws,
                                 bf16_t* __restrict__ Wtb) {
    int b = blockIdx.x;
    int n = b & 127;
    int matli = b >> 7;
    int mat = matli & 3, li = matli >> 2;
    int kk = threadIdx.x;
    const float* W = (mat == 0 ? Wq : mat == 1 ? Wk : mat == 2 ? Wv : Ws) + (size_t)li * HDIM * HDIM;
    float val = W[kk * HDIM + n];
    if (mat == 1) val *= SCALE;
    Wtb[((size_t)(li * 4 + mat) * HDIM + n) * HDIM + kk] = (bf16_t)val;
}

// ---------------------------------------------------------------------------
// Fused projection GEMM. blockIdx.y: 0 -> q (fp32), 1 -> k&v (packed half2,
// k pre-scaled, coalesced 4B stores), 2 -> skip (fp32).
__global__ __launch_bounds__(256) void gemm_mfma(
    const bf16_t* __restrict__ hb, const bf16_t* __restrict__ Wt,
    const float* __restrict__ bq, const float* __restrict__ bk,
    const float* __restrict__ bv, const float* __restrict__ bs,
    float* __restrict__ qo, __half2* __restrict__ kvh,
    float* __restrict__ so) {
    __shared__ bf16_t Ash[128 * 128];
    __shared__ bf16_t Bsh[128 * 128];
    int tid = threadIdx.x;
    int mt = blockIdx.y;
    int row0 = blockIdx.x * 128;
    int r = tid >> 4, g = tid & 15;

    {   // stage A and first B (q: slot0, kv: slot1=k, skip: slot3)
        const bf16_t* W0 = Wt + (size_t)(mt == 0 ? 0 : (mt == 1 ? 1 : 3)) * HDIM * HDIM;
#pragma unroll
        for (int p = 0; p < 8; ++p) {
            int rr = p * 16 + r;
            int sw = (g ^ (rr & 15)) << 3;
            *(bf16x8*)(Ash + rr * 128 + sw) = *(const bf16x8*)(hb + (size_t)(row0 + rr) * HDIM + g * 8);
            *(bf16x8*)(Bsh + rr * 128 + sw) = *(const bf16x8*)(W0 + (size_t)rr * HDIM + g * 8);
        }
    }
    __syncthreads();

    int lane = tid & 63, wave = tid >> 6;
    int wr = (wave >> 1) * 64, wc = (wave & 1) * 64;
    int lm = lane & 15, quad = lane >> 4;

    f32x4 acc[4][4];
#pragma unroll
    for (int i = 0; i < 4; ++i)
#pragma unroll
        for (int j = 0; j < 4; ++j) acc[i][j] = (f32x4){0.f, 0.f, 0.f, 0.f};

#pragma unroll
    for (int ks = 0; ks < 4; ++ks) {
        int gg = ks * 4 + quad;
        int sw = (gg ^ lm) << 3;
        bf16x8 af[4], bf[4];
#pragma unroll
        for (int t = 0; t < 4; ++t) {
            af[t] = *(const bf16x8*)(Ash + (wr + t * 16 + lm) * 128 + sw);
            bf[t] = *(const bf16x8*)(Bsh + (wc + t * 16 + lm) * 128 + sw);
        }
#pragma unroll
        for (int i = 0; i < 4; ++i)
#pragma unroll
            for (int j = 0; j < 4; ++j)
                acc[i][j] = __builtin_amdgcn_mfma_f32_16x16x32_bf16(af[i], bf[j], acc[i][j], 0, 0, 0);
    }

    if (mt == 1) {
        // second pass: v (slot 2)
        f32x4 acc2[4][4];
#pragma unroll
        for (int i = 0; i < 4; ++i)
#pragma unroll
            for (int j = 0; j < 4; ++j) acc2[i][j] = (f32x4){0.f, 0.f, 0.f, 0.f};
        __syncthreads();
        {
            const bf16_t* W1 = Wt + (size_t)2 * HDIM * HDIM;
#pragma unroll
            for (int p = 0; p < 8; ++p) {
                int rr = p * 16 + r;
                int sw = (g ^ (rr & 15)) << 3;
                *(bf16x8*)(Bsh + rr * 128 + sw) = *(const bf16x8*)(W1 + (size_t)rr * HDIM + g * 8);
            }
        }
        __syncthreads();
#pragma unroll
        for (int ks = 0; ks < 4; ++ks) {
            int gg = ks * 4 + quad;
            int sw = (gg ^ lm) << 3;
            bf16x8 af[4], bf[4];
#pragma unroll
            for (int t = 0; t < 4; ++t) {
                af[t] = *(const bf16x8*)(Ash + (wr + t * 16 + lm) * 128 + sw);
                bf[t] = *(const bf16x8*)(Bsh + (wc + t * 16 + lm) * 128 + sw);
            }
#pragma unroll
            for (int i = 0; i < 4; ++i)
#pragma unroll
                for (int j = 0; j < 4; ++j)
                    acc2[i][j] = __builtin_amdgcn_mfma_f32_16x16x32_bf16(af[i], bf[j], acc2[i][j], 0, 0, 0);
        }
        // packed epilogue: half2{k,v}, coalesced 4B stores
#pragma unroll
        for (int i = 0; i < 4; ++i) {
            int rbase = row0 + wr + i * 16 + quad * 4;
#pragma unroll
            for (int j = 0; j < 4; ++j) {
                int col = wc + j * 16 + lm;
                float kb = bk[col] * SCALE;
                float vb = bv[col];
#pragma unroll
                for (int rr2 = 0; rr2 < 4; ++rr2) {
                    int row = rbase + rr2;
                    if (row < N_NODES)
                        kvh[(size_t)row * HDIM + col] =
                            __floats2half2_rn(acc[i][j][rr2] + kb, acc2[i][j][rr2] + vb);
                }
            }
        }
    } else {
        const float* bias = (mt == 0) ? bq : bs;
        float* out = (mt == 0) ? qo : so;
#pragma unroll
        for (int i = 0; i < 4; ++i) {
            int rbase = row0 + wr + i * 16 + quad * 4;
#pragma unroll
            for (int j = 0; j < 4; ++j) {
                int col = wc + j * 16 + lm;
                float bcol = bias[col];
#pragma unroll
                for (int rr2 = 0; rr2 < 4; ++rr2) {
                    int row = rbase + rr2;
                    if (row < N_NODES) out[(size_t)row * HDIM + col] = acc[i][j][rr2] + bcol;
                }
            }
        }
    }
}

// ---------------------------------------------------------------------------
// Fused per-dst-node attention + skip + LayerNorm + ReLU.
// Per-head score-side edge-embedding dots computed in a per-node preamble
// (6 butterflies over 32-lane head groups — round-3-verified). Main loop
// uses 4-way edge ILP: 4 independent online-softmax states merged at end.
__global__ __launch_bounds__(128) void agg_kernel(
    const int* __restrict__ srcarr, const int* __restrict__ rowptr,
    const float* __restrict__ ea5,
    const float* __restrict__ q,
    const __half2* __restrict__ kv,
    const float* __restrict__ Me, const float* __restrict__ ce,
    const float* __restrict__ skip,
    const float* __restrict__ lg, const float* __restrict__ lb,
    bf16_t* __restrict__ hbout) {
    __shared__ float wred[2];
    int n = blockIdx.x;
    int t = threadIdx.x;
    int c = t & 31;
    int lane = t & 63;

    float qv = q[(size_t)n * HDIM + t];      // raw q (k is pre-scaled)
    float qs = qv * SCALE;                   // scaled copy for preamble dots
    float cw = ce[t];
    float mw[5];
#pragma unroll
    for (int j = 0; j < 5; ++j) mw[j] = Me[j * HDIM + t];

    // per-node, per-head preamble: myq = SCALE * (c<5 ? q_h.Me_c_h : c==5 ? q_h.ce_h : 0)
    float myq = 0.0f;
#pragma unroll
    for (int j = 0; j < 6; ++j) {
        float p = qs * ((j < 5) ? mw[j] : cw);
        p += __shfl_xor(p, 16, 32);
        p += __shfl_xor(p, 8, 32);
        p += __shfl_xor(p, 4, 32);
        p += __shfl_xor(p, 2, 32);
        p += __shfl_xor(p, 1, 32);
        if (c == j) myq = p;
    }

    int beg = rowptr[n], end = rowptr[n + 1];
    float m[4], l[4], o[4], ab[4];
#pragma unroll
    for (int s = 0; s < 4; ++s) { m[s] = -1e30f; l[s] = 0.f; o[s] = 0.f; ab[s] = 0.f; }

    for (int base = beg; base < end; base += 4) {
        int src4[4];
        float av4[4], kf4[4], vf4[4], p4[4];
#pragma unroll
        for (int s = 0; s < 4; ++s) {
            int idx = base + s;
            int cidx = (idx < end) ? idx : (end - 1);
            src4[s] = srcarr[cidx];
            av4[s] = (c < 5) ? ea5[(size_t)cidx * 5 + c] : 1.0f;
        }
#pragma unroll
        for (int s = 0; s < 4; ++s) {
            __half2 kvv = kv[(size_t)src4[s] * HDIM + t];
            kf4[s] = __low2float(kvv);
            vf4[s] = __high2float(kvv);
        }
#pragma unroll
        for (int s = 0; s < 4; ++s) p4[s] = fmaf(qv, kf4[s], myq * av4[s]);
        // 4 interleaved 32-lane butterflies
#pragma unroll
        for (int st = 16; st >= 1; st >>= 1) {
#pragma unroll
            for (int s = 0; s < 4; ++s) p4[s] += __shfl_xor(p4[s], st, 32);
        }
#pragma unroll
        for (int s = 0; s < 4; ++s) {
            float p = (base + s < end) ? p4[s] : -2e30f;  // masked -> pe = 0
            float mn = fmaxf(m[s], p);
            float sc = __expf(m[s] - mn);
            float pe = __expf(p - mn);
            o[s] = o[s] * sc + pe * vf4[s];
            l[s] = l[s] * sc + pe;
            ab[s] = ab[s] * sc + pe * av4[s];
            m[s] = mn;
        }
    }
    // merge 4 states -> state 0
#pragma unroll
    for (int step = 0; step < 3; ++step) {
        int a = (step == 2) ? 0 : (step == 0 ? 0 : 2);
        int b = (step == 2) ? 2 : (step == 0 ? 1 : 3);
        float mn = fmaxf(m[a], m[b]);
        float sa = __expf(m[a] - mn), sb = __expf(m[b] - mn);
        o[a] = o[a] * sa + o[b] * sb;
        l[a] = l[a] * sa + l[b] * sb;
        ab[a] = ab[a] * sa + ab[b] * sb;
        m[a] = mn;
    }

    // msg = (o + l*ce + sum_j Me_j * ab_j) / (l + 1e-16)
    float num = fmaf(l[0], cw, o[0]);
#pragma unroll
    for (int j = 0; j < 5; ++j) {
        float abj = __shfl(ab[0], (lane & 32) + j, 64);
        num = fmaf(mw[j], abj, num);
    }
    float msg = num / (l[0] + 1e-16f);
    float val = skip[(size_t)n * HDIM + t] + msg;

    // LayerNorm over 128 channels
    float s = val;
#pragma unroll
    for (int mask = 32; mask >= 1; mask >>= 1) s += __shfl_xor(s, mask, 64);
    if ((t & 63) == 0) wred[t >> 6] = s;
    __syncthreads();
    float mu = (wred[0] + wred[1]) * (1.0f / HDIM);
    float d = val - mu;
    float s2 = d * d;
#pragma unroll
    for (int mask = 32; mask >= 1; mask >>= 1) s2 += __shfl_xor(s2, mask, 64);
    __syncthreads();
    if ((t & 63) == 0) wred[t >> 6] = s2;
    __syncthreads();
    float var = (wred[0] + wred[1]) * (1.0f / HDIM);
    float y = d * rsqrtf(var + 1e-5f) * lg[t] + lb[t];
    y = fmaxf(y, 0.0f);
    hbout[(size_t)n * HDIM + t] = (bf16_t)y;
}

// ---------------------------------------------------------------------------
__global__ __launch_bounds__(128) void pool_kernel(const bf16_t* __restrict__ h,
                                                   const int* __restrict__ batch,
                                                   float* __restrict__ pool,
                                                   float* __restrict__ cnt) {
    int t = threadIdx.x;
    int n0 = blockIdx.x * POOL_CHUNK;
    int n1 = n0 + POOL_CHUNK;
    if (n1 > N_NODES) n1 = N_NODES;
    int gcur = batch[n0];
    int cstart = n0;
    float acc = 0.0f;
    for (int n = n0; n < n1; ++n) {
        int g = batch[n];
        if (g != gcur) {
            atomicAdd(&pool[gcur * HDIM + t], acc);
            if (t == 0) atomicAdd(&cnt[gcur], (float)(n - cstart));
            acc = 0.0f;
            gcur = g;
            cstart = n;
        }
        acc += (float)h[(size_t)n * HDIM + t];
    }
    atomicAdd(&pool[gcur * HDIM + t], acc);
    if (t == 0) atomicAdd(&cnt[gcur], (float)(n1 - cstart));
}

// ---------------------------------------------------------------------------
__global__ void heads_kernel(const float* __restrict__ pool,
                             const float* __restrict__ cnt,
                             const float* __restrict__ dw1, const float* __restrict__ db1,
                             const float* __restrict__ dw2, const float* __restrict__ db2,
                             const float* __restrict__ tw1, const float* __restrict__ tb1,
                             const float* __restrict__ tw2, const float* __restrict__ tb2,
                             float* __restrict__ outp) {
    int g = blockIdx.x, t = threadIdx.x;
    __shared__ float hg[HDIM];
    __shared__ float hid[64];
    float c = fmaxf(cnt[g], 1.0f);
    hg[t] = pool[g * HDIM + t] / c;
    __syncthreads();
    if (t < 64) {
        float s = db1[t];
        for (int i = 0; i < HDIM; ++i) s += hg[i] * dw1[i * 64 + t];
        hid[t] = fmaxf(s, 0.0f);
    }
    __syncthreads();
    if (t < ODIM) {
        float s = db2[t];
        for (int j = 0; j < 64; ++j) s += hid[j] * dw2[j * ODIM + t];
        outp[g * ODIM + t] = s;
    }
    __syncthreads();
    if (t < 64) {
        float s = tb1[t];
        for (int i = 0; i < HDIM; ++i) s += hg[i] * tw1[i * 64 + t];
        hid[t] = fmaxf(s, 0.0f);
    }
    __syncthreads();
    if (t < ODIM) {
        float s = tb2[t];
        for (int j = 0; j < 64; ++j) s += hid[j] * tw2[j * ODIM + t];
        outp[N_GRAPHS * ODIM + g * ODIM + t] = s;
    }
}

// ---------------------------------------------------------------------------
extern "C" void kernel_launch(void* const* d_in, const int* in_sizes, int n_in,
                              void* d_out, int out_size, void* d_ws, size_t ws_size,
                              hipStream_t stream) {
    const float* x        = (const float*)d_in[0];
    const float* ea       = (const float*)d_in[1];
    const float* node_w   = (const float*)d_in[2];
    const float* node_b   = (const float*)d_in[3];
    const float* edge_w   = (const float*)d_in[4];
    const float* edge_b   = (const float*)d_in[5];
    const float* Wq       = (const float*)d_in[6];
    const float* bq       = (const float*)d_in[7];
    const float* Wk       = (const float*)d_in[8];
    const float* bk       = (const float*)d_in[9];
    const float* Wv       = (const float*)d_in[10];
    const float* bv       = (const float*)d_in[11];
    const float* We       = (const float*)d_in[12];
    const float* Wskip    = (const float*)d_in[13];
    const float* bskip    = (const float*)d_in[14];
    const float* ln_g     = (const float*)d_in[15];
    const float* ln_b     = (const float*)d_in[16];
    const float* dw1      = (const float*)d_in[17];
    const float* db1      = (const float*)d_in[18];
    const float* dw2      = (const float*)d_in[19];
    const float* db2      = (const float*)d_in[20];
    const float* tw1      = (const float*)d_in[21];
    const float* tb1      = (const float*)d_in[22];
    const float* tw2      = (const float*)d_in[23];
    const float* tb2      = (const float*)d_in[24];
    const int*   ei       = (const int*)d_in[25];
    const int*   batch    = (const int*)d_in[26];
    float* out = (float*)d_out;
    (void)in_sizes; (void)n_in; (void)out_size; (void)ws_size;

    // ---- workspace carve (256B aligned) ----
    char* wsb = (char*)d_ws;
    size_t off = 0;
    auto carve = [&](size_t bytes) -> void* {
        void* p = wsb + off;
        off += (bytes + 255) & ~(size_t)255;
        return p;
    };
    bf16_t*  hbuf   = (bf16_t*) carve((size_t)M_PAD * HDIM * 2);
    float*   q      = (float*)  carve((size_t)N_NODES * HDIM * 4);
    __half2* kvh    = (__half2*)carve((size_t)N_NODES * HDIM * 4);
    float*   ob     = (float*)  carve((size_t)N_NODES * HDIM * 4);   // skip buffer
    bf16_t*  Wtb    = (bf16_t*) carve((size_t)NLAYERS * 4 * HDIM * HDIM * 2);
    int*     srcarr = (int*)    carve((size_t)N_EDGES * 4);
    float*   ea5    = (float*)  carve((size_t)N_EDGES * 5 * 4);
    int*     deg    = (int*)    carve((size_t)N_NODES * 4);
    int*     rowptr = (int*)    carve((size_t)(N_NODES + 1) * 4);
    int*     cursor = (int*)    carve((size_t)N_NODES * 4);
    int*     bsum   = (int*)    carve((size_t)SCAN_NBLK * 4);
    int*     bscan  = (int*)    carve((size_t)SCAN_NBLK * 4);
    float*   Me_all = (float*)  carve((size_t)NLAYERS * 5 * HDIM * 4);
    float*   ce_all = (float*)  carve((size_t)NLAYERS * HDIM * 4);
    float*   pool   = (float*)  carve((size_t)N_GRAPHS * HDIM * 4);
    float*   cnt    = (float*)  carve((size_t)N_GRAPHS * 4);

    const int nthreads = 256;
    const int e_blocks  = (N_EDGES + nthreads - 1) / nthreads;
    const int nc_blocks = (N_NODES * HDIM) / nthreads;

    // ---- CSR build ----
    hipMemsetAsync(deg, 0, (size_t)N_NODES * 4, stream);
    hipMemsetAsync(cursor, 0, (size_t)N_NODES * 4, stream);
    count_deg_kernel<<<e_blocks, nthreads, 0, stream>>>(ei, deg);
    scan1_kernel<<<SCAN_NBLK, SCAN_B, 0, stream>>>(deg, rowptr, bsum);
    scan2_kernel<<<1, SCAN_B, 0, stream>>>(bsum, bscan);
    scan3_kernel<<<SCAN_NBLK, SCAN_B, 0, stream>>>(rowptr, bscan);
    fill_csr_kernel<<<e_blocks, nthreads, 0, stream>>>(ei, ea, rowptr, cursor, srcarr, ea5);

    // ---- projections / weight prep ----
    hipMemsetAsync(hbuf + (size_t)N_NODES * HDIM, 0,
                   (size_t)(M_PAD - N_NODES) * HDIM * 2, stream);  // zero pad rows
    nodeproj_kernel<<<nc_blocks, nthreads, 0, stream>>>(x, node_w, node_b, hbuf);
    fold_edge_kernel<<<NLAYERS * 6, HDIM, 0, stream>>>(edge_w, edge_b, We, Me_all, ce_all);
    convert_w_kernel<<<NLAYERS * 4 * HDIM, HDIM, 0, stream>>>(Wq, Wk, Wv, Wskip, Wtb);

    for (int i = 0; i < NLAYERS; ++i) {
        const float* Me = Me_all + i * 5 * HDIM;
        const float* ce = ce_all + i * HDIM;
        gemm_mfma<<<dim3(M_PAD / 128, 3), 256, 0, stream>>>(
            hbuf, Wtb + (size_t)i * 4 * HDIM * HDIM,
            bq + i * HDIM, bk + i * HDIM, bv + i * HDIM, bskip + i * HDIM,
            q, kvh, ob);
        agg_kernel<<<N_NODES, 128, 0, stream>>>(srcarr, rowptr, ea5, q, kvh,
                                                Me, ce, ob,
                                                ln_g + i * HDIM, ln_b + i * HDIM, hbuf);
    }

    hipMemsetAsync(pool, 0, (size_t)N_GRAPHS * HDIM * 4, stream);
    hipMemsetAsync(cnt, 0, (size_t)N_GRAPHS * 4, stream);
    pool_kernel<<<POOL_NBLK, HDIM, 0, stream>>>(hbuf, batch, pool, cnt);
    heads_kernel<<<N_GRAPHS, HDIM, 0, stream>>>(pool, cnt, dw1, db1, dw2, db2,
                                                tw1, tb1, tw2, tb2, out);
}

// Round 7
// 773.434 us; speedup vs baseline: 1.3670x; 1.0904x over previous
//
#include <hip/hip_runtime.h>
#include <hip/hip_fp16.h>
#include <math.h>

#define N_NODES 40000
#define N_EDGES 640000
#define N_GRAPHS 32
#define HDIM 128
#define NHEADS 4
#define CDIM 32
#define NLAYERS 4
#define ODIM 100
#define SCAN_B 256
#define SCAN_NBLK ((N_NODES + SCAN_B - 1) / SCAN_B)   // 157
#define M_PAD 40064                                   // 313 * 128
#define POOL_CHUNK 256
#define POOL_NBLK ((N_NODES + POOL_CHUNK - 1) / POOL_CHUNK)  // 157
#define SCALE 0.17677669529663687f                    // 1/sqrt(32)

typedef __bf16 bf16_t;
typedef bf16_t bf16x8 __attribute__((ext_vector_type(8)));
typedef float f32x4 __attribute__((ext_vector_type(4)));

// packed k/v pair for one (channel, channel+16) pair of one node
struct __align__(8) H2P { __half2 k; __half2 v; };

// ---------------------------------------------------------------------------
// h = x @ node_w + node_b   ([N,4]@[4,128]) -> bf16 feature buffer
__global__ void nodeproj_kernel(const float* __restrict__ x,
                                const float* __restrict__ w,
                                const float* __restrict__ b,
                                bf16_t* __restrict__ hb) {
    int idx = blockIdx.x * blockDim.x + threadIdx.x;
    if (idx >= N_NODES * HDIM) return;
    int n = idx >> 7, c = idx & 127;
    float s = b[c];
    s += x[n * 4 + 0] * w[0 * HDIM + c];
    s += x[n * 4 + 1] * w[1 * HDIM + c];
    s += x[n * 4 + 2] * w[2 * HDIM + c];
    s += x[n * 4 + 3] * w[3 * HDIM + c];
    hb[idx] = (bf16_t)s;
}

// ---------------------------------------------------------------------------
// Me[i] = edge_w @ We[i]  ([5,128]),  ce[i] = edge_b @ We[i]  ([128])
__global__ void fold_edge_kernel(const float* __restrict__ edge_w,
                                 const float* __restrict__ edge_b,
                                 const float* __restrict__ We,
                                 float* __restrict__ Me_all,
                                 float* __restrict__ ce_all) {
    int blk = blockIdx.x;
    int i = blk / 6, j = blk % 6;
    int c = threadIdx.x;
    const float* W = We + (size_t)i * HDIM * HDIM;
    float s = 0.0f;
    if (j < 5) {
        for (int k = 0; k < HDIM; ++k) s += edge_w[j * HDIM + k] * W[k * HDIM + c];
        Me_all[i * 5 * HDIM + j * HDIM + c] = s;
    } else {
        for (int k = 0; k < HDIM; ++k) s += edge_b[k] * W[k * HDIM + c];
        ce_all[i * HDIM + c] = s;
    }
}

// ---------------------------------------------------------------------------
// CSR build
__global__ void count_deg_kernel(const int* __restrict__ ei, int* __restrict__ deg) {
    int e = blockIdx.x * blockDim.x + threadIdx.x;
    if (e >= N_EDGES) return;
    atomicAdd(&deg[ei[N_EDGES + e]], 1);
}

__global__ void scan1_kernel(const int* __restrict__ deg,
                             int* __restrict__ rowptr, int* __restrict__ bsum) {
    __shared__ int sd[SCAN_B];
    int tid = threadIdx.x;
    int i = blockIdx.x * SCAN_B + tid;
    int v = (i < N_NODES) ? deg[i] : 0;
    sd[tid] = v;
    __syncthreads();
#pragma unroll
    for (int off = 1; off < SCAN_B; off <<= 1) {
        int tmp = (tid >= off) ? sd[tid - off] : 0;
        __syncthreads();
        sd[tid] += tmp;
        __syncthreads();
    }
    if (i < N_NODES) rowptr[i] = sd[tid] - v;
    if (tid == SCAN_B - 1) bsum[blockIdx.x] = sd[tid];
}

__global__ void scan2_kernel(const int* __restrict__ bsum, int* __restrict__ bscan) {
    __shared__ int sd[SCAN_B];
    int tid = threadIdx.x;
    int v = (tid < SCAN_NBLK) ? bsum[tid] : 0;
    sd[tid] = v;
    __syncthreads();
#pragma unroll
    for (int off = 1; off < SCAN_B; off <<= 1) {
        int tmp = (tid >= off) ? sd[tid - off] : 0;
        __syncthreads();
        sd[tid] += tmp;
        __syncthreads();
    }
    if (tid < SCAN_NBLK) bscan[tid] = sd[tid] - v;
}

__global__ void scan3_kernel(int* __restrict__ rowptr, const int* __restrict__ bscan) {
    int i = blockIdx.x * SCAN_B + threadIdx.x;
    if (i < N_NODES) rowptr[i] += bscan[blockIdx.x];
    if (i == 0) rowptr[N_NODES] = N_EDGES;
}

__global__ void fill_csr_kernel(const int* __restrict__ ei,
                                const float* __restrict__ ea,
                                const int* __restrict__ rowptr,
                                int* __restrict__ cursor,
                                int* __restrict__ srcarr,
                                float* __restrict__ ea5) {
    int e = blockIdx.x * blockDim.x + threadIdx.x;
    if (e >= N_EDGES) return;
    int src = ei[e], dst = ei[N_EDGES + e];
    int pos = atomicAdd(&cursor[dst], 1);
    int p = rowptr[dst] + pos;
    srcarr[p] = src;
#pragma unroll
    for (int j = 0; j < 5; ++j) ea5[(size_t)p * 5 + j] = ea[(size_t)e * 5 + j];
}

// ---------------------------------------------------------------------------
// Convert weights to bf16 [n][k]; Wk pre-scaled by 1/sqrt(C).
__global__ void convert_w_kernel(const float* __restrict__ Wq, const float* __restrict__ Wk,
                                 const float* __restrict__ Wv, const float* __restrict__ Ws,
                                 bf16_t* __restrict__ Wtb) {
    int b = blockIdx.x;
    int n = b & 127;
    int matli = b >> 7;
    int mat = matli & 3, li = matli >> 2;
    int kk = threadIdx.x;
    const float* W = (mat == 0 ? Wq : mat == 1 ? Wk : mat == 2 ? Wv : Ws) + (size_t)li * HDIM * HDIM;
    float val = W[kk * HDIM + n];
    if (mat == 1) val *= SCALE;
    Wtb[((size_t)(li * 4 + mat) * HDIM + n) * HDIM + kk] = (bf16_t)val;
}

// ---------------------------------------------------------------------------
// Fused projection GEMM. blockIdx.y: 0 -> q (packed half2 pairs),
// 1 -> k&v (H2P pairs, k pre-scaled), 2 -> skip (fp32).
// Pair layout: low channel c in {0..15,32..47,64..79,96..111}, pair=(c,c+16),
// pair index pi = ((c>>5)<<4)|(c&15). MFMA C-layout: lane lm holds cols
// wc+lm+j*16 (j=0..3), so pairs (j0,j1) and (j2,j3) are lane-local.
__global__ __launch_bounds__(256) void gemm_mfma(
    const bf16_t* __restrict__ hb, const bf16_t* __restrict__ Wt,
    const float* __restrict__ bq, const float* __restrict__ bk,
    const float* __restrict__ bv, const float* __restrict__ bs,
    __half2* __restrict__ q2o, H2P* __restrict__ kv2o,
    float* __restrict__ so) {
    __shared__ bf16_t Ash[128 * 128];
    __shared__ bf16_t Bsh[128 * 128];
    int tid = threadIdx.x;
    int mt = blockIdx.y;
    int row0 = blockIdx.x * 128;
    int r = tid >> 4, g = tid & 15;

    {   // stage A and first B (q: slot0, kv: slot1=k, skip: slot3)
        const bf16_t* W0 = Wt + (size_t)(mt == 0 ? 0 : (mt == 1 ? 1 : 3)) * HDIM * HDIM;
#pragma unroll
        for (int p = 0; p < 8; ++p) {
            int rr = p * 16 + r;
            int sw = (g ^ (rr & 15)) << 3;
            *(bf16x8*)(Ash + rr * 128 + sw) = *(const bf16x8*)(hb + (size_t)(row0 + rr) * HDIM + g * 8);
            *(bf16x8*)(Bsh + rr * 128 + sw) = *(const bf16x8*)(W0 + (size_t)rr * HDIM + g * 8);
        }
    }
    __syncthreads();

    int lane = tid & 63, wave = tid >> 6;
    int wr = (wave >> 1) * 64, wc = (wave & 1) * 64;
    int lm = lane & 15, quad = lane >> 4;

    f32x4 acc[4][4];
#pragma unroll
    for (int i = 0; i < 4; ++i)
#pragma unroll
        for (int j = 0; j < 4; ++j) acc[i][j] = (f32x4){0.f, 0.f, 0.f, 0.f};

#pragma unroll
    for (int ks = 0; ks < 4; ++ks) {
        int gg = ks * 4 + quad;
        int sw = (gg ^ lm) << 3;
        bf16x8 af[4], bf[4];
#pragma unroll
        for (int t = 0; t < 4; ++t) {
            af[t] = *(const bf16x8*)(Ash + (wr + t * 16 + lm) * 128 + sw);
            bf[t] = *(const bf16x8*)(Bsh + (wc + t * 16 + lm) * 128 + sw);
        }
#pragma unroll
        for (int i = 0; i < 4; ++i)
#pragma unroll
            for (int j = 0; j < 4; ++j)
                acc[i][j] = __builtin_amdgcn_mfma_f32_16x16x32_bf16(af[i], bf[j], acc[i][j], 0, 0, 0);
    }

    int c0 = wc + lm;           // low channel of pair (j0,j1)
    int c2 = wc + lm + 32;      // low channel of pair (j2,j3)
    int pi0 = ((c0 >> 5) << 4) | lm;
    int pi1 = ((c2 >> 5) << 4) | lm;

    if (mt == 0) {
        float b0 = bq[c0], b1 = bq[c0 + 16], b2 = bq[c2], b3 = bq[c2 + 16];
#pragma unroll
        for (int i = 0; i < 4; ++i) {
            int rbase = row0 + wr + i * 16 + quad * 4;
#pragma unroll
            for (int rr2 = 0; rr2 < 4; ++rr2) {
                int row = rbase + rr2;
                if (row < N_NODES) {
                    q2o[(size_t)row * 64 + pi0] =
                        __floats2half2_rn(acc[i][0][rr2] + b0, acc[i][1][rr2] + b1);
                    q2o[(size_t)row * 64 + pi1] =
                        __floats2half2_rn(acc[i][2][rr2] + b2, acc[i][3][rr2] + b3);
                }
            }
        }
    } else if (mt == 1) {
        // second pass: v (slot 2)
        f32x4 acc2[4][4];
#pragma unroll
        for (int i = 0; i < 4; ++i)
#pragma unroll
            for (int j = 0; j < 4; ++j) acc2[i][j] = (f32x4){0.f, 0.f, 0.f, 0.f};
        __syncthreads();
        {
            const bf16_t* W1 = Wt + (size_t)2 * HDIM * HDIM;
#pragma unroll
            for (int p = 0; p < 8; ++p) {
                int rr = p * 16 + r;
                int sw = (g ^ (rr & 15)) << 3;
                *(bf16x8*)(Bsh + rr * 128 + sw) = *(const bf16x8*)(W1 + (size_t)rr * HDIM + g * 8);
            }
        }
        __syncthreads();
#pragma unroll
        for (int ks = 0; ks < 4; ++ks) {
            int gg = ks * 4 + quad;
            int sw = (gg ^ lm) << 3;
            bf16x8 af[4], bf[4];
#pragma unroll
            for (int t = 0; t < 4; ++t) {
                af[t] = *(const bf16x8*)(Ash + (wr + t * 16 + lm) * 128 + sw);
                bf[t] = *(const bf16x8*)(Bsh + (wc + t * 16 + lm) * 128 + sw);
            }
#pragma unroll
            for (int i = 0; i < 4; ++i)
#pragma unroll
                for (int j = 0; j < 4; ++j)
                    acc2[i][j] = __builtin_amdgcn_mfma_f32_16x16x32_bf16(af[i], bf[j], acc2[i][j], 0, 0, 0);
        }
        float kb0 = bk[c0] * SCALE, kb1 = bk[c0 + 16] * SCALE;
        float kb2 = bk[c2] * SCALE, kb3 = bk[c2 + 16] * SCALE;
        float vb0 = bv[c0], vb1 = bv[c0 + 16], vb2 = bv[c2], vb3 = bv[c2 + 16];
#pragma unroll
        for (int i = 0; i < 4; ++i) {
            int rbase = row0 + wr + i * 16 + quad * 4;
#pragma unroll
            for (int rr2 = 0; rr2 < 4; ++rr2) {
                int row = rbase + rr2;
                if (row < N_NODES) {
                    H2P h0, h1;
                    h0.k = __floats2half2_rn(acc[i][0][rr2] + kb0, acc[i][1][rr2] + kb1);
                    h0.v = __floats2half2_rn(acc2[i][0][rr2] + vb0, acc2[i][1][rr2] + vb1);
                    h1.k = __floats2half2_rn(acc[i][2][rr2] + kb2, acc[i][3][rr2] + kb3);
                    h1.v = __floats2half2_rn(acc2[i][2][rr2] + vb2, acc2[i][3][rr2] + vb3);
                    kv2o[(size_t)row * 64 + pi0] = h0;
                    kv2o[(size_t)row * 64 + pi1] = h1;
                }
            }
        }
    } else {
#pragma unroll
        for (int i = 0; i < 4; ++i) {
            int rbase = row0 + wr + i * 16 + quad * 4;
#pragma unroll
            for (int j = 0; j < 4; ++j) {
                int col = wc + j * 16 + lm;
                float bcol = bs[col];
#pragma unroll
                for (int rr2 = 0; rr2 < 4; ++rr2) {
                    int row = rbase + rr2;
                    if (row < N_NODES) so[(size_t)row * HDIM + col] = acc[i][j][rr2] + bcol;
                }
            }
        }
    }
}

// ---------------------------------------------------------------------------
// Fused per-dst-node attention + skip + LayerNorm + ReLU.
// ONE WAVE per node; lane t owns channel pair (clo, clo+16), clo =
// ((t>>4)<<5)|(t&15) -- head = t>>4 spans 16 lanes, butterfly = 4 stages.
// 4-way edge ILP; no LDS, no barriers. Block = 256 threads = 4 nodes.
__global__ __launch_bounds__(256) void agg_kernel(
    const int* __restrict__ srcarr, const int* __restrict__ rowptr,
    const float* __restrict__ ea5,
    const __half2* __restrict__ q2,
    const H2P* __restrict__ kv2,
    const float* __restrict__ Me, const float* __restrict__ ce,
    const float* __restrict__ skip,
    const float* __restrict__ lg, const float* __restrict__ lb,
    bf16_t* __restrict__ hbout) {
    int t = threadIdx.x & 63;
    int n = blockIdx.x * 4 + (threadIdx.x >> 6);
    int cc = t & 15;
    int clo = ((t >> 4) << 5) | cc;
    int chi = clo + 16;

    float2 qf = __half22float2(q2[(size_t)n * 64 + t]);
    float cwlo = ce[clo], cwhi = ce[chi];
    float mlo[5], mhi[5];
#pragma unroll
    for (int j = 0; j < 5; ++j) { mlo[j] = Me[j * HDIM + clo]; mhi[j] = Me[j * HDIM + chi]; }

    // per-node per-head preamble: lane cc==j gets SCALE * (q_h . Mvec_j_h)
    float myq = 0.0f;
#pragma unroll
    for (int j = 0; j < 6; ++j) {
        float a = (j < 5) ? mlo[j] : cwlo;
        float b = (j < 5) ? mhi[j] : cwhi;
        float p = (qf.x * a + qf.y * b) * SCALE;
        p += __shfl_xor(p, 8, 16);
        p += __shfl_xor(p, 4, 16);
        p += __shfl_xor(p, 2, 16);
        p += __shfl_xor(p, 1, 16);
        if (cc == j) myq = p;
    }

    int beg = rowptr[n], end = rowptr[n + 1];
    float m[4], l[4], o0[4], o1[4], ab[4];
#pragma unroll
    for (int s = 0; s < 4; ++s) { m[s] = -1e30f; l[s] = 0.f; o0[s] = 0.f; o1[s] = 0.f; ab[s] = 0.f; }

    for (int base = beg; base < end; base += 4) {
        float av4[4], p4[4];
        float2 kf4[4], vf4[4];
#pragma unroll
        for (int s = 0; s < 4; ++s) {
            int idx = base + s;
            int cidx = (idx < end) ? idx : (end - 1);
            int src = srcarr[cidx];
            av4[s] = (cc < 5) ? ea5[(size_t)cidx * 5 + cc] : 1.0f;
            H2P kvv = kv2[(size_t)src * 64 + t];
            kf4[s] = __half22float2(kvv.k);
            vf4[s] = __half22float2(kvv.v);
        }
#pragma unroll
        for (int s = 0; s < 4; ++s)
            p4[s] = fmaf(qf.x, kf4[s].x, fmaf(qf.y, kf4[s].y, myq * av4[s]));
        // 4 interleaved 16-lane butterflies
#pragma unroll
        for (int st = 8; st >= 1; st >>= 1) {
#pragma unroll
            for (int s = 0; s < 4; ++s) p4[s] += __shfl_xor(p4[s], st, 16);
        }
#pragma unroll
        for (int s = 0; s < 4; ++s) {
            float p = (base + s < end) ? p4[s] : -2e30f;  // wave-uniform mask -> pe=0
            float mn = fmaxf(m[s], p);
            float sc = __expf(m[s] - mn);
            float pe = __expf(p - mn);
            o0[s] = o0[s] * sc + pe * vf4[s].x;
            o1[s] = o1[s] * sc + pe * vf4[s].y;
            l[s] = l[s] * sc + pe;
            ab[s] = ab[s] * sc + pe * av4[s];
            m[s] = mn;
        }
    }
    // merge 4 states -> state 0
#pragma unroll
    for (int step = 0; step < 3; ++step) {
        int a = (step == 2) ? 0 : (step == 0 ? 0 : 2);
        int b = (step == 2) ? 2 : (step == 0 ? 1 : 3);
        float mn = fmaxf(m[a], m[b]);
        float sa = __expf(m[a] - mn), sb = __expf(m[b] - mn);
        o0[a] = o0[a] * sa + o0[b] * sb;
        o1[a] = o1[a] * sa + o1[b] * sb;
        l[a] = l[a] * sa + l[b] * sb;
        ab[a] = ab[a] * sa + ab[b] * sb;
        m[a] = mn;
    }

    // msg = (o + l*ce + sum_j Me_j * ab_j) / (l + 1e-16)
    float nlo = fmaf(l[0], cwlo, o0[0]);
    float nhi = fmaf(l[0], cwhi, o1[0]);
#pragma unroll
    for (int j = 0; j < 5; ++j) {
        float abj = __shfl(ab[0], (t & 48) + j, 64);
        nlo = fmaf(mlo[j], abj, nlo);
        nhi = fmaf(mhi[j], abj, nhi);
    }
    float inv = 1.0f / (l[0] + 1e-16f);
    float vlo = skip[(size_t)n * HDIM + clo] + nlo * inv;
    float vhi = skip[(size_t)n * HDIM + chi] + nhi * inv;

    // LayerNorm over 128 channels -- single-wave butterfly
    float s = vlo + vhi;
#pragma unroll
    for (int mask = 32; mask >= 1; mask >>= 1) s += __shfl_xor(s, mask, 64);
    float mu = s * (1.0f / HDIM);
    float dlo = vlo - mu, dhi = vhi - mu;
    float s2 = dlo * dlo + dhi * dhi;
#pragma unroll
    for (int mask = 32; mask >= 1; mask >>= 1) s2 += __shfl_xor(s2, mask, 64);
    float rstd = rsqrtf(s2 * (1.0f / HDIM) + 1e-5f);
    float ylo = fmaxf(dlo * rstd * lg[clo] + lb[clo], 0.0f);
    float yhi = fmaxf(dhi * rstd * lg[chi] + lb[chi], 0.0f);
    hbout[(size_t)n * HDIM + clo] = (bf16_t)ylo;
    hbout[(size_t)n * HDIM + chi] = (bf16_t)yhi;
}

// ---------------------------------------------------------------------------
__global__ __launch_bounds__(128) void pool_kernel(const bf16_t* __restrict__ h,
                                                   const int* __restrict__ batch,
                                                   float* __restrict__ pool,
                                                   float* __restrict__ cnt) {
    int t = threadIdx.x;
    int n0 = blockIdx.x * POOL_CHUNK;
    int n1 = n0 + POOL_CHUNK;
    if (n1 > N_NODES) n1 = N_NODES;
    int gcur = batch[n0];
    int cstart = n0;
    float acc = 0.0f;
    for (int n = n0; n < n1; ++n) {
        int g = batch[n];
        if (g != gcur) {
            atomicAdd(&pool[gcur * HDIM + t], acc);
            if (t == 0) atomicAdd(&cnt[gcur], (float)(n - cstart));
            acc = 0.0f;
            gcur = g;
            cstart = n;
        }
        acc += (float)h[(size_t)n * HDIM + t];
    }
    atomicAdd(&pool[gcur * HDIM + t], acc);
    if (t == 0) atomicAdd(&cnt[gcur], (float)(n1 - cstart));
}

// ---------------------------------------------------------------------------
__global__ void heads_kernel(const float* __restrict__ pool,
                             const float* __restrict__ cnt,
                             const float* __restrict__ dw1, const float* __restrict__ db1,
                             const float* __restrict__ dw2, const float* __restrict__ db2,
                             const float* __restrict__ tw1, const float* __restrict__ tb1,
                             const float* __restrict__ tw2, const float* __restrict__ tb2,
                             float* __restrict__ outp) {
    int g = blockIdx.x, t = threadIdx.x;
    __shared__ float hg[HDIM];
    __shared__ float hid[64];
    float c = fmaxf(cnt[g], 1.0f);
    hg[t] = pool[g * HDIM + t] / c;
    __syncthreads();
    if (t < 64) {
        float s = db1[t];
        for (int i = 0; i < HDIM; ++i) s += hg[i] * dw1[i * 64 + t];
        hid[t] = fmaxf(s, 0.0f);
    }
    __syncthreads();
    if (t < ODIM) {
        float s = db2[t];
        for (int j = 0; j < 64; ++j) s += hid[j] * dw2[j * ODIM + t];
        outp[g * ODIM + t] = s;
    }
    __syncthreads();
    if (t < 64) {
        float s = tb1[t];
        for (int i = 0; i < HDIM; ++i) s += hg[i] * tw1[i * 64 + t];
        hid[t] = fmaxf(s, 0.0f);
    }
    __syncthreads();
    if (t < ODIM) {
        float s = tb2[t];
        for (int j = 0; j < 64; ++j) s += hid[j] * tw2[j * ODIM + t];
        outp[N_GRAPHS * ODIM + g * ODIM + t] = s;
    }
}

// ---------------------------------------------------------------------------
extern "C" void kernel_launch(void* const* d_in, const int* in_sizes, int n_in,
                              void* d_out, int out_size, void* d_ws, size_t ws_size,
                              hipStream_t stream) {
    const float* x        = (const float*)d_in[0];
    const float* ea       = (const float*)d_in[1];
    const float* node_w   = (const float*)d_in[2];
    const float* node_b   = (const float*)d_in[3];
    const float* edge_w   = (const float*)d_in[4];
    const float* edge_b   = (const float*)d_in[5];
    const float* Wq       = (const float*)d_in[6];
    const float* bq       = (const float*)d_in[7];
    const float* Wk       = (const float*)d_in[8];
    const float* bk       = (const float*)d_in[9];
    const float* Wv       = (const float*)d_in[10];
    const float* bv       = (const float*)d_in[11];
    const float* We       = (const float*)d_in[12];
    const float* Wskip    = (const float*)d_in[13];
    const float* bskip    = (const float*)d_in[14];
    const float* ln_g     = (const float*)d_in[15];
    const float* ln_b     = (const float*)d_in[16];
    const float* dw1      = (const float*)d_in[17];
    const float* db1      = (const float*)d_in[18];
    const float* dw2      = (const float*)d_in[19];
    const float* db2      = (const float*)d_in[20];
    const float* tw1      = (const float*)d_in[21];
    const float* tb1      = (const float*)d_in[22];
    const float* tw2      = (const float*)d_in[23];
    const float* tb2      = (const float*)d_in[24];
    const int*   ei       = (const int*)d_in[25];
    const int*   batch    = (const int*)d_in[26];
    float* out = (float*)d_out;
    (void)in_sizes; (void)n_in; (void)out_size; (void)ws_size;

    // ---- workspace carve (256B aligned) ----
    char* wsb = (char*)d_ws;
    size_t off = 0;
    auto carve = [&](size_t bytes) -> void* {
        void* p = wsb + off;
        off += (bytes + 255) & ~(size_t)255;
        return p;
    };
    bf16_t*  hbuf   = (bf16_t*) carve((size_t)M_PAD * HDIM * 2);
    __half2* q2b    = (__half2*)carve((size_t)N_NODES * 64 * 4);
    H2P*     kv2b   = (H2P*)    carve((size_t)N_NODES * 64 * 8);
    float*   ob     = (float*)  carve((size_t)N_NODES * HDIM * 4);   // skip buffer
    bf16_t*  Wtb    = (bf16_t*) carve((size_t)NLAYERS * 4 * HDIM * HDIM * 2);
    int*     srcarr = (int*)    carve((size_t)N_EDGES * 4);
    float*   ea5    = (float*)  carve((size_t)N_EDGES * 5 * 4);
    int*     deg    = (int*)    carve((size_t)N_NODES * 4);
    int*     rowptr = (int*)    carve((size_t)(N_NODES + 1) * 4);
    int*     cursor = (int*)    carve((size_t)N_NODES * 4);
    int*     bsum   = (int*)    carve((size_t)SCAN_NBLK * 4);
    int*     bscan  = (int*)    carve((size_t)SCAN_NBLK * 4);
    float*   Me_all = (float*)  carve((size_t)NLAYERS * 5 * HDIM * 4);
    float*   ce_all = (float*)  carve((size_t)NLAYERS * HDIM * 4);
    float*   pool   = (float*)  carve((size_t)N_GRAPHS * HDIM * 4);
    float*   cnt    = (float*)  carve((size_t)N_GRAPHS * 4);

    const int nthreads = 256;
    const int e_blocks  = (N_EDGES + nthreads - 1) / nthreads;
    const int nc_blocks = (N_NODES * HDIM) / nthreads;

    // ---- CSR build ----
    hipMemsetAsync(deg, 0, (size_t)N_NODES * 4, stream);
    hipMemsetAsync(cursor, 0, (size_t)N_NODES * 4, stream);
    count_deg_kernel<<<e_blocks, nthreads, 0, stream>>>(ei, deg);
    scan1_kernel<<<SCAN_NBLK, SCAN_B, 0, stream>>>(deg, rowptr, bsum);
    scan2_kernel<<<1, SCAN_B, 0, stream>>>(bsum, bscan);
    scan3_kernel<<<SCAN_NBLK, SCAN_B, 0, stream>>>(rowptr, bscan);
    fill_csr_kernel<<<e_blocks, nthreads, 0, stream>>>(ei, ea, rowptr, cursor, srcarr, ea5);

    // ---- projections / weight prep ----
    hipMemsetAsync(hbuf + (size_t)N_NODES * HDIM, 0,
                   (size_t)(M_PAD - N_NODES) * HDIM * 2, stream);  // zero pad rows
    nodeproj_kernel<<<nc_blocks, nthreads, 0, stream>>>(x, node_w, node_b, hbuf);
    fold_edge_kernel<<<NLAYERS * 6, HDIM, 0, stream>>>(edge_w, edge_b, We, Me_all, ce_all);
    convert_w_kernel<<<NLAYERS * 4 * HDIM, HDIM, 0, stream>>>(Wq, Wk, Wv, Wskip, Wtb);

    for (int i = 0; i < NLAYERS; ++i) {
        const float* Me = Me_all + i * 5 * HDIM;
        const float* ce = ce_all + i * HDIM;
        gemm_mfma<<<dim3(M_PAD / 128, 3), 256, 0, stream>>>(
            hbuf, Wtb + (size_t)i * 4 * HDIM * HDIM,
            bq + i * HDIM, bk + i * HDIM, bv + i * HDIM, bskip + i * HDIM,
            q2b, kv2b, ob);
        agg_kernel<<<N_NODES / 4, 256, 0, stream>>>(srcarr, rowptr, ea5, q2b, kv2b,
                                                    Me, ce, ob,
                                                    ln_g + i * HDIM, ln_b + i * HDIM, hbuf);
    }

    hipMemsetAsync(pool, 0, (size_t)N_GRAPHS * HDIM * 4, stream);
    hipMemsetAsync(cnt, 0, (size_t)N_GRAPHS * 4, stream);
    pool_kernel<<<POOL_NBLK, HDIM, 0, stream>>>(hbuf, batch, pool, cnt);
    heads_kernel<<<N_GRAPHS, HDIM, 0, stream>>>(pool, cnt, dw1, db1, dw2, db2,
                                                tw1, tb1, tw2, tb2, out);
}